// Round 5
// baseline (87.917 us; speedup 1.0000x reference)
//
#include <hip/hip_runtime.h>
#include <math.h>

// BatchPitNorm1d — B=512, S=2048, F=128
//   u[b,f] = mean_s Phi((x[b,f]-cdf[s,f]) / sigmoid(bwp[f]));  out = ndtri(u)
//
// Table method: u(x) per feature is smooth+monotone. Build fp32 partial sums of
// (signed small-terms, exp(-z^2/2), count-positive) on a G=64 uniform x-grid per
// feature; then one fused kernel reduces the partials for the two bracketing grid
// rows and cubic-Hermite interpolates (exact analytic slopes) + fp64 ndtri.
// Evals: G*S*F = 16.8M vs direct B*S*F = 134M (8x).
#define FDIM  128
#define SDIM  2048
#define BDIM  512
#define GPTS  64            // grid points
#define SP    16            // S-partitions across blocks (occupancy: 1024 blocks)
#define PARTS 4             // S-partitions within block (threads per f)
#define BLOCK1 (FDIM * PARTS)
#define XMIN  (-6.0)
#define XSPAN (12.0)        // grid covers [-6.0, 6.0]; max|x|~4.3 for 64k normals

// ---------------- AS241 (Wichura) PPND16 inverse normal CDF, fp64 ----------
// Takes both u and cu = 1-u, each with full relative accuracy -> both tails precise.
__device__ __forceinline__ double ndtri_pair(double u, double cu) {
    double q = u - 0.5;
    if (fabs(q) <= 0.425) {
        double r = 0.180625 - q * q;
        double num = (((((((2.5090809287301226727e3  * r + 3.3430575583588128105e4) * r +
                            6.7265770927008700853e4) * r + 4.5921953931549871457e4) * r +
                            1.3731693765509461125e4) * r + 1.9715909503065514427e3) * r +
                            1.3314166789178437745e2) * r + 3.3871328727963666080e0);
        double den = (((((((5.2264952788528545610e3  * r + 2.8729085735721942674e4) * r +
                            3.9307895800092710610e4) * r + 2.1213794301586595867e4) * r +
                            5.3941960214247511077e3) * r + 6.8718700749205790830e2) * r +
                            4.2313330701600911252e1) * r + 1.0);
        return q * num / den;
    }
    double r = (q < 0.0) ? u : cu;
    r = fmax(r, 1e-300);
    r = sqrt(-log(r));
    double val;
    if (r <= 5.0) {
        r -= 1.6;
        double num = (((((((7.74545014278341407640e-4 * r + 2.27238449892691845833e-2) * r +
                            2.41780725177450611770e-1) * r + 1.27045825245236838258e0) * r +
                            3.64784832476320460504e0)  * r + 5.76949722146069140550e0) * r +
                            4.63033784615654529590e0)  * r + 1.42343711074968357734e0);
        double den = (((((((1.05075007164441684324e-9 * r + 5.47593808499534494600e-4) * r +
                            1.51986665636164571966e-2) * r + 1.48103976427480074590e-1) * r +
                            6.89767334985100004550e-1) * r + 1.67638483018380384940e0) * r +
                            2.05319162663775882187e0)  * r + 1.0);
        val = num / den;
    } else {
        r -= 5.0;
        double num = (((((((2.01033439929228813265e-7 * r + 2.71155556874348757815e-5) * r +
                            1.24266094738807843860e-3) * r + 2.65321895265761230930e-2) * r +
                            2.96560571828504891230e-1) * r + 1.78482653991729133580e0) * r +
                            5.46378491116411436990e0)  * r + 6.65790464350110377720e0);
        double den = (((((((2.04426310338993978564e-15 * r + 1.42151175831644588870e-7) * r +
                            1.84631831751005468180e-5)  * r + 7.86869131145613259100e-4) * r +
                            1.48753612908506148525e-2)  * r + 1.36929880922735805310e-1) * r +
                            5.99832206555887937690e-1)  * r + 1.0);
        val = num / den;
    }
    return (q < 0.0) ? -val : val;
}

// e = 0.5*erfc(a), a>=0, A&S 7.1.26 (abs err ~7.5e-8); also returns ex=exp(-a^2)
__device__ __forceinline__ float half_erfc_ex(float a, float& ex_out) {
    float t  = __builtin_amdgcn_rcpf(fmaf(0.3275911f, a, 1.0f));
    float ex = __expf(-a * a);
    ex_out = ex;
    float q  = fmaf(0.53070271450f, t, -0.72657601350f);
    q        = fmaf(q, t,  0.71070687050f);
    q        = fmaf(q, t, -0.14224836800f);
    q        = fmaf(q, t,  0.12741479600f);
    return q * t * ex;
}

// ---------- K1: per-(gridpoint, S-chunk) partial sums -----------------------
// blockIdx.x = g*SP + sp; 512 threads = 128 f x 4 parts; 32 samples/thread.
// 1024 blocks -> 4 blocks/CU co-resident (32 waves/CU, 100% occupancy).
__global__ __launch_bounds__(BLOCK1) void build_kernel(
    const float* __restrict__ cdf, const float* __restrict__ bwp,
    float* __restrict__ accP, float* __restrict__ dacP, int* __restrict__ npP)
{
    const int g    = blockIdx.x >> 4;          // /SP
    const int sp   = blockIdx.x & (SP - 1);
    const int f    = threadIdx.x & (FDIM - 1);
    const int part = threadIdx.x >> 7;

    const float p = bwp[f];
    const float s = (1.0f + __expf(-p)) * 0.70710678118654752f;
    const float xg = (float)(XMIN + (double)g * (XSPAN / (GPTS - 1)));

    const int chunk = SDIM / SP / PARTS;       // 32 samples
    const int base  = sp * (SDIM / SP) + part * chunk;
    const float* cp = cdf + base * FDIM + f;

    // Phi(z) = (z>=0) ? 1-e : e.  Track exact integer npos + signed small-term
    // sum so both tails of u keep full relative precision (ndtri amplifies ~2e4x).
    float acc0 = 0.f, acc1 = 0.f, acc2 = 0.f, acc3 = 0.f;
    float dac = 0.f;
    int npos = 0;

    #pragma unroll 2
    for (int i = 0; i < chunk; i += 4) {
        float c0 = cp[0 * FDIM];
        float c1 = cp[1 * FDIM];
        float c2 = cp[2 * FDIM];
        float c3 = cp[3 * FDIM];
        cp += 4 * FDIM;

        float d0 = xg - c0, d1 = xg - c1, d2 = xg - c2, d3 = xg - c3;
        float x0, x1, x2, x3;
        float e0 = half_erfc_ex(fabsf(d0) * s, x0);
        float e1 = half_erfc_ex(fabsf(d1) * s, x1);
        float e2 = half_erfc_ex(fabsf(d2) * s, x2);
        float e3 = half_erfc_ex(fabsf(d3) * s, x3);

        bool p0 = d0 >= 0.f, p1 = d1 >= 0.f, p2 = d2 >= 0.f, p3 = d3 >= 0.f;
        acc0 += p0 ? -e0 : e0;
        acc1 += p1 ? -e1 : e1;
        acc2 += p2 ? -e2 : e2;
        acc3 += p3 ? -e3 : e3;
        npos += (int)p0 + (int)p1 + (int)p2 + (int)p3;
        dac  += (x0 + x1) + (x2 + x3);         // sum exp(-z^2/2) for du/dx
    }

    __shared__ float sacc[PARTS][FDIM];
    __shared__ float sdac[PARTS][FDIM];
    __shared__ int   snp[PARTS][FDIM];
    sacc[part][f] = (acc0 + acc1) + (acc2 + acc3);
    sdac[part][f] = dac;
    snp[part][f]  = npos;
    __syncthreads();

    if (part == 0) {
        float a  = (sacc[0][f] + sacc[1][f]) + (sacc[2][f] + sacc[3][f]);
        float da = (sdac[0][f] + sdac[1][f]) + (sdac[2][f] + sdac[3][f]);
        int   np = snp[0][f] + snp[1][f] + snp[2][f] + snp[3][f];
        const int o = blockIdx.x * FDIM + f;   // (g*SP+sp)*FDIM + f
        accP[o] = a;
        dacP[o] = da;
        npP[o]  = np;
    }
}

// ---------- K2 (fused): reduce partials for 2 bracketing rows + Hermite + ndtri
__global__ __launch_bounds__(256) void interp_kernel(
    const float* __restrict__ x, const float* __restrict__ bwp,
    const float* __restrict__ accP, const float* __restrict__ dacP,
    const int* __restrict__ npP, float* __restrict__ out)
{
    const int idx = blockIdx.x * 256 + threadIdx.x;   // b*FDIM + f
    const int f = idx & (FDIM - 1);

    double t = ((double)x[idx] - XMIN) * ((GPTS - 1) / XSPAN);
    t = fmin(fmax(t, 0.0), (double)(GPTS - 1));
    int i = (int)t;
    if (i > GPTS - 2) i = GPTS - 2;
    double w = t - (double)i;

    // reduce SP partials for grid rows i and i+1 (all L2-hot)
    double a0 = 0.0, da0 = 0.0, a1 = 0.0, da1 = 0.0;
    int np0 = 0, np1 = 0;
    const float* pA = accP + (i * SP) * FDIM + f;
    const float* pD = dacP + (i * SP) * FDIM + f;
    const int*   pN = npP  + (i * SP) * FDIM + f;
    #pragma unroll
    for (int sp = 0; sp < SP; ++sp) {
        a0  += (double)pA[sp * FDIM];
        da0 += (double)pD[sp * FDIM];
        np0 += pN[sp * FDIM];
        a1  += (double)pA[(SP + sp) * FDIM];
        da1 += (double)pD[(SP + sp) * FDIM];
        np1 += pN[(SP + sp) * FDIM];
    }

    // node values: u = (np + a)/S ; cu = ((S-np) - a)/S ; slope m = da*invbw/(S*sqrt(2pi))
    const double invS = 1.0 / (double)SDIM;
    const double invbw = 1.0 + (double)__expf(-bwp[f]);
    const double mscale = invbw * (invS / 2.5066282746310002);
    double u0 = ((double)np0 + a0) * invS;
    double cu0 = ((double)(SDIM - np0) - a0) * invS;
    double m0 = da0 * mscale;
    double u1 = ((double)np1 + a1) * invS;
    double cu1 = ((double)(SDIM - np1) - a1) * invS;
    double m1 = da1 * mscale;

    // cubic Hermite, H = grid step
    const double H = XSPAN / (GPTS - 1);
    double w2 = w * w, w3 = w2 * w;
    double h00 = 2.0 * w3 - 3.0 * w2 + 1.0;
    double h10 = w3 - 2.0 * w2 + w;
    double h01 = 3.0 * w2 - 2.0 * w3;
    double h11 = w3 - w2;
    double dterm = H * (h10 * m0 + h11 * m1);
    double u  = h00 * u0 + h01 * u1 + dterm;
    double cu = h00 * cu0 + h01 * cu1 - dterm;

    out[idx] = (float)ndtri_pair(u, cu);
}

extern "C" void kernel_launch(void* const* d_in, const int* in_sizes, int n_in,
                              void* d_out, int out_size, void* d_ws, size_t ws_size,
                              hipStream_t stream) {
    const float* x   = (const float*)d_in[0];   // [512,128]
    const float* cdf = (const float*)d_in[1];   // [2048,128]
    const float* bwp = (const float*)d_in[2];   // [1,128]
    float* out = (float*)d_out;

    const size_t GSPF = (size_t)GPTS * SP * FDIM;   // 131072
    float* accP = (float*)d_ws;                     // 512KB
    float* dacP = accP + GSPF;                      // 512KB
    int*   npP  = (int*)(dacP + GSPF);              // 512KB -> 1.5MB total

    build_kernel<<<dim3(GPTS * SP), dim3(BLOCK1), 0, stream>>>(cdf, bwp, accP, dacP, npP);
    interp_kernel<<<dim3((BDIM * FDIM) / 256), dim3(256), 0, stream>>>(x, bwp, accP, dacP, npP, out);
}

// Round 6
// 72.348 us; speedup vs baseline: 1.2152x; 1.2152x over previous
//
#include <hip/hip_runtime.h>
#include <math.h>

// BatchPitNorm1d — B=512, S=2048, F=128
//   u[b,f] = mean_s Phi((x[b,f]-cdf[s,f]) / sigmoid(bwp[f]));  out = ndtri(u)
//
// Table method: u(x) per feature is smooth+monotone. K1 builds fp32 partial sums
// on a G=64 uniform x-grid (16.8M evals vs direct 134M). K2 reduces SP partials
// -> fp64 (u, 1-u, du/dx) tables with COALESCED loads (lane = f, shared g; the
// R5 fused variant gathered per-lane-divergent rows and fragmented every load
// into ~64 transactions — 25 us regression). K3 does a tiny 6-load gather +
// cubic Hermite (exact analytic slopes) + fp64 ndtri per output element.
#define FDIM  128
#define SDIM  2048
#define BDIM  512
#define GPTS  64            // grid points
#define SP    16            // S-partitions across blocks (1024 blocks, 4/CU)
#define PARTS 4             // S-partitions within block (threads per f)
#define BLOCK1 (FDIM * PARTS)
#define XMIN  (-6.0)
#define XSPAN (12.0)        // grid covers [-6.0, 6.0]; max|x|~4.3 for 64k normals

// ---------------- AS241 (Wichura) PPND16 inverse normal CDF, fp64 ----------
// Takes both u and cu = 1-u, each with full relative accuracy -> both tails precise.
__device__ __forceinline__ double ndtri_pair(double u, double cu) {
    double q = u - 0.5;
    if (fabs(q) <= 0.425) {
        double r = 0.180625 - q * q;
        double num = (((((((2.5090809287301226727e3  * r + 3.3430575583588128105e4) * r +
                            6.7265770927008700853e4) * r + 4.5921953931549871457e4) * r +
                            1.3731693765509461125e4) * r + 1.9715909503065514427e3) * r +
                            1.3314166789178437745e2) * r + 3.3871328727963666080e0);
        double den = (((((((5.2264952788528545610e3  * r + 2.8729085735721942674e4) * r +
                            3.9307895800092710610e4) * r + 2.1213794301586595867e4) * r +
                            5.3941960214247511077e3) * r + 6.8718700749205790830e2) * r +
                            4.2313330701600911252e1) * r + 1.0);
        return q * num / den;
    }
    double r = (q < 0.0) ? u : cu;
    r = fmax(r, 1e-300);
    r = sqrt(-log(r));
    double val;
    if (r <= 5.0) {
        r -= 1.6;
        double num = (((((((7.74545014278341407640e-4 * r + 2.27238449892691845833e-2) * r +
                            2.41780725177450611770e-1) * r + 1.27045825245236838258e0) * r +
                            3.64784832476320460504e0)  * r + 5.76949722146069140550e0) * r +
                            4.63033784615654529590e0)  * r + 1.42343711074968357734e0);
        double den = (((((((1.05075007164441684324e-9 * r + 5.47593808499534494600e-4) * r +
                            1.51986665636164571966e-2) * r + 1.48103976427480074590e-1) * r +
                            6.89767334985100004550e-1) * r + 1.67638483018380384940e0) * r +
                            2.05319162663775882187e0)  * r + 1.0);
        val = num / den;
    } else {
        r -= 5.0;
        double num = (((((((2.01033439929228813265e-7 * r + 2.71155556874348757815e-5) * r +
                            1.24266094738807843860e-3) * r + 2.65321895265761230930e-2) * r +
                            2.96560571828504891230e-1) * r + 1.78482653991729133580e0) * r +
                            5.46378491116411436990e0)  * r + 6.65790464350110377720e0);
        double den = (((((((2.04426310338993978564e-15 * r + 1.42151175831644588870e-7) * r +
                            1.84631831751005468180e-5)  * r + 7.86869131145613259100e-4) * r +
                            1.48753612908506148525e-2)  * r + 1.36929880922735805310e-1) * r +
                            5.99832206555887937690e-1)  * r + 1.0);
        val = num / den;
    }
    return (q < 0.0) ? -val : val;
}

// e = 0.5*erfc(a), a>=0, A&S 7.1.26 (abs err ~7.5e-8); also returns ex=exp(-a^2)
__device__ __forceinline__ float half_erfc_ex(float a, float& ex_out) {
    float t  = __builtin_amdgcn_rcpf(fmaf(0.3275911f, a, 1.0f));
    float ex = __expf(-a * a);
    ex_out = ex;
    float q  = fmaf(0.53070271450f, t, -0.72657601350f);
    q        = fmaf(q, t,  0.71070687050f);
    q        = fmaf(q, t, -0.14224836800f);
    q        = fmaf(q, t,  0.12741479600f);
    return q * t * ex;
}

// ---------- K1: per-(gridpoint, S-chunk) partial sums -----------------------
// blockIdx.x = g*SP + sp; 512 threads = 128 f x 4 parts; 32 samples/thread.
__global__ __launch_bounds__(BLOCK1) void build_kernel(
    const float* __restrict__ cdf, const float* __restrict__ bwp,
    float* __restrict__ accP, float* __restrict__ dacP, int* __restrict__ npP)
{
    const int g    = blockIdx.x >> 4;          // /SP
    const int sp   = blockIdx.x & (SP - 1);
    const int f    = threadIdx.x & (FDIM - 1);
    const int part = threadIdx.x >> 7;

    const float p = bwp[f];
    const float s = (1.0f + __expf(-p)) * 0.70710678118654752f;
    const float xg = (float)(XMIN + (double)g * (XSPAN / (GPTS - 1)));

    const int chunk = SDIM / SP / PARTS;       // 32 samples
    const int base  = sp * (SDIM / SP) + part * chunk;
    const float* cp = cdf + base * FDIM + f;

    // Phi(z) = (z>=0) ? 1-e : e.  Exact integer npos + signed small-term sum:
    // both tails of u keep full relative precision (ndtri amplifies ~2e4x).
    float acc0 = 0.f, acc1 = 0.f, acc2 = 0.f, acc3 = 0.f;
    float dac = 0.f;
    int npos = 0;

    #pragma unroll 2
    for (int i = 0; i < chunk; i += 4) {
        float c0 = cp[0 * FDIM];
        float c1 = cp[1 * FDIM];
        float c2 = cp[2 * FDIM];
        float c3 = cp[3 * FDIM];
        cp += 4 * FDIM;

        float d0 = xg - c0, d1 = xg - c1, d2 = xg - c2, d3 = xg - c3;
        float x0, x1, x2, x3;
        float e0 = half_erfc_ex(fabsf(d0) * s, x0);
        float e1 = half_erfc_ex(fabsf(d1) * s, x1);
        float e2 = half_erfc_ex(fabsf(d2) * s, x2);
        float e3 = half_erfc_ex(fabsf(d3) * s, x3);

        bool p0 = d0 >= 0.f, p1 = d1 >= 0.f, p2 = d2 >= 0.f, p3 = d3 >= 0.f;
        acc0 += p0 ? -e0 : e0;
        acc1 += p1 ? -e1 : e1;
        acc2 += p2 ? -e2 : e2;
        acc3 += p3 ? -e3 : e3;
        npos += (int)p0 + (int)p1 + (int)p2 + (int)p3;
        dac  += (x0 + x1) + (x2 + x3);         // sum exp(-z^2/2) for du/dx
    }

    __shared__ float sacc[PARTS][FDIM];
    __shared__ float sdac[PARTS][FDIM];
    __shared__ int   snp[PARTS][FDIM];
    sacc[part][f] = (acc0 + acc1) + (acc2 + acc3);
    sdac[part][f] = dac;
    snp[part][f]  = npos;
    __syncthreads();

    if (part == 0) {
        float a  = (sacc[0][f] + sacc[1][f]) + (sacc[2][f] + sacc[3][f]);
        float da = (sdac[0][f] + sdac[1][f]) + (sdac[2][f] + sdac[3][f]);
        int   np = snp[0][f] + snp[1][f] + snp[2][f] + snp[3][f];
        const int o = blockIdx.x * FDIM + f;   // (g*SP+sp)*FDIM + f
        accP[o] = a;
        dacP[o] = da;
        npP[o]  = np;
    }
}

// ---------- K2: reduce SP partials -> fp64 table (u, 1-u, du/dx) ------------
// Coalesced: lane = f, row g shared per 2 waves; 48 contiguous 256B loads/thread-group.
__global__ __launch_bounds__(256) void table_kernel(
    const float* __restrict__ accP, const float* __restrict__ dacP,
    const int* __restrict__ npP, const float* __restrict__ bwp,
    double* __restrict__ Tu, double* __restrict__ Tcu, double* __restrict__ Td)
{
    const int idx = blockIdx.x * 256 + threadIdx.x;   // [0, GPTS*FDIM)
    const int f = idx & (FDIM - 1);
    const int g = idx >> 7;

    double a = 0.0, da = 0.0;
    int np = 0;
    const float* pA = accP + (g * SP) * FDIM + f;
    const float* pD = dacP + (g * SP) * FDIM + f;
    const int*   pN = npP  + (g * SP) * FDIM + f;
    #pragma unroll
    for (int sp = 0; sp < SP; ++sp) {
        a  += (double)pA[sp * FDIM];
        da += (double)pD[sp * FDIM];
        np += pN[sp * FDIM];
    }
    const double invS = 1.0 / (double)SDIM;
    double invbw = 1.0 + exp(-(double)bwp[f]);
    Tu[idx]  = ((double)np + a) * invS;
    Tcu[idx] = ((double)(SDIM - np) - a) * invS;
    // du/dx = (invbw/(S*sqrt(2pi))) * sum exp(-z^2/2)
    Td[idx]  = da * invbw * (invS / 2.5066282746310002);
}

// ---------- K3: cubic Hermite interpolation + ndtri (6 gathered loads) ------
__global__ __launch_bounds__(256) void interp_kernel(
    const float* __restrict__ x,
    const double* __restrict__ Tu, const double* __restrict__ Tcu,
    const double* __restrict__ Td, float* __restrict__ out)
{
    const int idx = blockIdx.x * 256 + threadIdx.x;   // b*FDIM + f
    const int f = idx & (FDIM - 1);

    const double H = XSPAN / (GPTS - 1);
    double t = ((double)x[idx] - XMIN) * ((GPTS - 1) / XSPAN);
    t = fmin(fmax(t, 0.0), (double)(GPTS - 1));
    int i = (int)t;
    if (i > GPTS - 2) i = GPTS - 2;
    double w = t - (double)i;

    const int o0 = i * FDIM + f;
    const int o1 = o0 + FDIM;
    double u0 = Tu[o0],  u1 = Tu[o1];
    double c0 = Tcu[o0], c1 = Tcu[o1];
    double m0 = Td[o0],  m1 = Td[o1];

    double w2 = w * w, w3 = w2 * w;
    double h00 = 2.0 * w3 - 3.0 * w2 + 1.0;
    double h10 = w3 - 2.0 * w2 + w;
    double h01 = 3.0 * w2 - 2.0 * w3;
    double h11 = w3 - w2;
    double dterm = H * (h10 * m0 + h11 * m1);
    double u  = h00 * u0 + h01 * u1 + dterm;
    double cu = h00 * c0 + h01 * c1 - dterm;

    out[idx] = (float)ndtri_pair(u, cu);
}

extern "C" void kernel_launch(void* const* d_in, const int* in_sizes, int n_in,
                              void* d_out, int out_size, void* d_ws, size_t ws_size,
                              hipStream_t stream) {
    const float* x   = (const float*)d_in[0];   // [512,128]
    const float* cdf = (const float*)d_in[1];   // [2048,128]
    const float* bwp = (const float*)d_in[2];   // [1,128]
    float* out = (float*)d_out;

    const size_t GF   = (size_t)GPTS * FDIM;        // 8192
    const size_t GSPF = (size_t)GPTS * SP * FDIM;   // 131072
    char* wsb = (char*)d_ws;
    double* Tu   = (double*)wsb;                    // 64KB
    double* Tcu  = Tu + GF;                         // 64KB
    double* Td   = Tcu + GF;                        // 64KB
    float*  accP = (float*)(Td + GF);               // 512KB
    float*  dacP = accP + GSPF;                     // 512KB
    int*    npP  = (int*)(dacP + GSPF);             // 512KB -> ~1.7MB total

    build_kernel<<<dim3(GPTS * SP), dim3(BLOCK1), 0, stream>>>(cdf, bwp, accP, dacP, npP);
    table_kernel<<<dim3(GF / 256), dim3(256), 0, stream>>>(accP, dacP, npP, bwp, Tu, Tcu, Td);
    interp_kernel<<<dim3((BDIM * FDIM) / 256), dim3(256), 0, stream>>>(x, Tu, Tcu, Td, out);
}

// Round 7
// 71.857 us; speedup vs baseline: 1.2235x; 1.0068x over previous
//
#include <hip/hip_runtime.h>
#include <math.h>

// BatchPitNorm1d — B=512, S=2048, F=128
//   u[b,f] = mean_s Phi((x[b,f]-cdf[s,f]) / sigmoid(bwp[f]));  out = ndtri(u)
//
// Table method, 2 kernels:
//  K1: fp32 partial sums (signed small-terms a, gauss-sum da, count np) on a
//      G=48 uniform x-grid, S split 16 ways; partials stored FEATURE-MAJOR
//      [f][sp][g] float4 so K2 can bulk-copy a contiguous per-feature slab.
//  K2 (fused): each block owns 4 features x 64 batch rows. Coalesced copy of
//      its 49KB partial slab -> LDS, conflict-free sp-reduction -> fp64 table
//      (u, 1-u, du/dx) in LDS, then cubic-Hermite (exact analytic slopes) +
//      fp64 pair-ndtri per output. (R5 showed per-lane divergent global
//      gathers of partials cost ~25us; LDS staging keeps every access clean.)
// Error model (h^4, validated R4->R6): interp err = 7.8e-3 at h=12/63 ->
// G=48 (h=12/47) gives ~2.5e-2 vs threshold 8e-2.
#define FDIM  128
#define SDIM  2048
#define BDIM  512
#define GPTS  48
#define SP    16
#define PARTS 4
#define BLOCK1 (FDIM * PARTS)
#define XMIN  (-6.0)
#define XSPAN (12.0)
#define FG    4             // features per K2 block
#define BG    64            // batch rows per K2 block
#define BLOCK2 256
#define PERF  (SP * GPTS)   // 768 partial entries per feature

// ---------------- AS241 (Wichura) PPND16 inverse normal CDF, fp64 ----------
__device__ __forceinline__ double ndtri_pair(double u, double cu) {
    double q = u - 0.5;
    if (fabs(q) <= 0.425) {
        double r = 0.180625 - q * q;
        double num = (((((((2.5090809287301226727e3  * r + 3.3430575583588128105e4) * r +
                            6.7265770927008700853e4) * r + 4.5921953931549871457e4) * r +
                            1.3731693765509461125e4) * r + 1.9715909503065514427e3) * r +
                            1.3314166789178437745e2) * r + 3.3871328727963666080e0);
        double den = (((((((5.2264952788528545610e3  * r + 2.8729085735721942674e4) * r +
                            3.9307895800092710610e4) * r + 2.1213794301586595867e4) * r +
                            5.3941960214247511077e3) * r + 6.8718700749205790830e2) * r +
                            4.2313330701600911252e1) * r + 1.0);
        return q * num / den;
    }
    double r = (q < 0.0) ? u : cu;
    r = fmax(r, 1e-300);
    r = sqrt(-log(r));
    double val;
    if (r <= 5.0) {
        r -= 1.6;
        double num = (((((((7.74545014278341407640e-4 * r + 2.27238449892691845833e-2) * r +
                            2.41780725177450611770e-1) * r + 1.27045825245236838258e0) * r +
                            3.64784832476320460504e0)  * r + 5.76949722146069140550e0) * r +
                            4.63033784615654529590e0)  * r + 1.42343711074968357734e0);
        double den = (((((((1.05075007164441684324e-9 * r + 5.47593808499534494600e-4) * r +
                            1.51986665636164571966e-2) * r + 1.48103976427480074590e-1) * r +
                            6.89767334985100004550e-1) * r + 1.67638483018380384940e0) * r +
                            2.05319162663775882187e0)  * r + 1.0);
        val = num / den;
    } else {
        r -= 5.0;
        double num = (((((((2.01033439929228813265e-7 * r + 2.71155556874348757815e-5) * r +
                            1.24266094738807843860e-3) * r + 2.65321895265761230930e-2) * r +
                            2.96560571828504891230e-1) * r + 1.78482653991729133580e0) * r +
                            5.46378491116411436990e0)  * r + 6.65790464350110377720e0);
        double den = (((((((2.04426310338993978564e-15 * r + 1.42151175831644588870e-7) * r +
                            1.84631831751005468180e-5)  * r + 7.86869131145613259100e-4) * r +
                            1.48753612908506148525e-2)  * r + 1.36929880922735805310e-1) * r +
                            5.99832206555887937690e-1)  * r + 1.0);
        val = num / den;
    }
    return (q < 0.0) ? -val : val;
}

// ---------- K1: per-(gridpoint, S-chunk) partial sums -----------------------
// blockIdx.x = g*SP + sp; 512 threads = 128 f x 4 parts; 32 samples/thread.
__global__ __launch_bounds__(BLOCK1) void build_kernel(
    const float* __restrict__ cdf, const float* __restrict__ bwp,
    float4* __restrict__ part4)
{
    const int g    = blockIdx.x >> 4;          // /SP
    const int sp   = blockIdx.x & (SP - 1);
    const int f    = threadIdx.x & (FDIM - 1);
    const int part = threadIdx.x >> 7;

    const float p = bwp[f];
    const float s = (1.0f + __expf(-p)) * 0.70710678118654752f;  // invbw/sqrt2
    const float c1s    = 0.3275911f * s;                         // folds a=|d|*s into t-arg
    const float negs2l = -(s * s) * 1.4426950408889634f;         // exp(-a^2)=exp2(d^2*negs2l)
    const float xg = (float)(XMIN + (double)g * (XSPAN / (GPTS - 1)));

    const int chunk = SDIM / SP / PARTS;       // 32 samples
    const int base  = sp * (SDIM / SP) + part * chunk;
    const float* cp = cdf + base * FDIM + f;

    // Phi(z) = (z>=0) ? 1-e : e,  e = 0.5*erfc(|z|/sqrt2) (A&S 7.1.26, ~7.5e-8).
    // Exact integer npos + signed small-term sum keeps both tails of u at full
    // relative precision (ndtri amplifies tail error ~2.6e4x, measured R3/R4).
    float acc0 = 0.f, acc1 = 0.f, acc2 = 0.f, acc3 = 0.f;
    float dac = 0.f;
    int npos = 0;

    #pragma unroll 2
    for (int i = 0; i < chunk; i += 4) {
        float c0 = cp[0 * FDIM];
        float c1 = cp[1 * FDIM];
        float c2 = cp[2 * FDIM];
        float c3 = cp[3 * FDIM];
        cp += 4 * FDIM;

        float d0 = xg - c0, d1 = xg - c1, d2 = xg - c2, d3 = xg - c3;

        float t0 = __builtin_amdgcn_rcpf(fmaf(c1s, fabsf(d0), 1.0f));
        float t1 = __builtin_amdgcn_rcpf(fmaf(c1s, fabsf(d1), 1.0f));
        float t2 = __builtin_amdgcn_rcpf(fmaf(c1s, fabsf(d2), 1.0f));
        float t3 = __builtin_amdgcn_rcpf(fmaf(c1s, fabsf(d3), 1.0f));

        float x0 = exp2f(d0 * d0 * negs2l);
        float x1 = exp2f(d1 * d1 * negs2l);
        float x2 = exp2f(d2 * d2 * negs2l);
        float x3 = exp2f(d3 * d3 * negs2l);

        float q0 = fmaf(0.53070271450f, t0, -0.72657601350f);
        float q1 = fmaf(0.53070271450f, t1, -0.72657601350f);
        float q2 = fmaf(0.53070271450f, t2, -0.72657601350f);
        float q3 = fmaf(0.53070271450f, t3, -0.72657601350f);
        q0 = fmaf(q0, t0, 0.71070687050f);  q1 = fmaf(q1, t1, 0.71070687050f);
        q2 = fmaf(q2, t2, 0.71070687050f);  q3 = fmaf(q3, t3, 0.71070687050f);
        q0 = fmaf(q0, t0, -0.14224836800f); q1 = fmaf(q1, t1, -0.14224836800f);
        q2 = fmaf(q2, t2, -0.14224836800f); q3 = fmaf(q3, t3, -0.14224836800f);
        q0 = fmaf(q0, t0, 0.12741479600f);  q1 = fmaf(q1, t1, 0.12741479600f);
        q2 = fmaf(q2, t2, 0.12741479600f);  q3 = fmaf(q3, t3, 0.12741479600f);

        float e0 = q0 * t0 * x0;
        float e1 = q1 * t1 * x1;
        float e2 = q2 * t2 * x2;
        float e3 = q3 * t3 * x3;

        bool p0 = d0 >= 0.f, p1 = d1 >= 0.f, p2 = d2 >= 0.f, p3 = d3 >= 0.f;
        acc0 += p0 ? -e0 : e0;
        acc1 += p1 ? -e1 : e1;
        acc2 += p2 ? -e2 : e2;
        acc3 += p3 ? -e3 : e3;
        npos += (int)p0 + (int)p1 + (int)p2 + (int)p3;
        dac  += (x0 + x1) + (x2 + x3);         // sum exp(-z^2/2) for du/dx
    }

    __shared__ float sacc[PARTS][FDIM];
    __shared__ float sdac[PARTS][FDIM];
    __shared__ int   snp[PARTS][FDIM];
    sacc[part][f] = (acc0 + acc1) + (acc2 + acc3);
    sdac[part][f] = dac;
    snp[part][f]  = npos;
    __syncthreads();

    if (part == 0) {
        float a  = (sacc[0][f] + sacc[1][f]) + (sacc[2][f] + sacc[3][f]);
        float da = (sdac[0][f] + sdac[1][f]) + (sdac[2][f] + sdac[3][f]);
        int   np = snp[0][f] + snp[1][f] + snp[2][f] + snp[3][f];
        // feature-major layout [f][sp][g]: scattered store (128 lines/wave) but
        // fire-and-forget; makes K2's slab copy perfectly contiguous.
        part4[f * PERF + sp * GPTS + g] = make_float4(a, da, (float)np, 0.f);
    }
}

// ---------- K2 (fused): slab->LDS, sp-reduce, fp64 table, Hermite + ndtri ----
// grid = 32 f-groups x 8 b-groups = 256 blocks x 256 threads.
__global__ __launch_bounds__(BLOCK2) void interp_kernel(
    const float* __restrict__ x, const float* __restrict__ bwp,
    const float4* __restrict__ part4, float* __restrict__ out)
{
    const int fg = blockIdx.x & 31;
    const int bg = blockIdx.x >> 5;
    const int F0 = fg * FG;
    const int B0 = bg * BG;
    const int tid = threadIdx.x;

    __shared__ float4 sp4[FG * PERF];          // 3072 * 16B = 48KB
    __shared__ double tab[FG * GPTS][3];       // 192 * 24B = 4.6KB

    // phase 1: contiguous coalesced copy of this block's 4-feature slab
    const float4* src = part4 + (size_t)F0 * PERF;
    #pragma unroll
    for (int k = tid; k < FG * PERF; k += BLOCK2) sp4[k] = src[k];
    __syncthreads();

    // phase 2: reduce SP partials per (fi,g) row; consecutive lanes read
    // consecutive float4s (contiguous b128 pattern, conflict-free).
    if (tid < FG * GPTS) {                     // 192 rows
        const int fi = tid / GPTS;
        const int g  = tid - fi * GPTS;
        double a = 0.0, da = 0.0, np = 0.0;
        const int base = fi * PERF + g;
        #pragma unroll
        for (int sp = 0; sp < SP; ++sp) {
            float4 v = sp4[base + sp * GPTS];
            a  += (double)v.x;
            da += (double)v.y;
            np += (double)v.z;                 // integer-valued, exact in fp32
        }
        const double invS = 1.0 / (double)SDIM;
        const double invbw = 1.0 + exp(-(double)bwp[F0 + fi]);
        tab[tid][0] = (np + a) * invS;                         // u
        tab[tid][1] = (((double)SDIM - np) - a) * invS;        // 1-u
        tab[tid][2] = da * invbw * (invS / 2.5066282746310002); // du/dx
    }
    __syncthreads();

    // phase 3: interpolate + ndtri.  lanes: 4 consecutive f per b (16B segs).
    const int bl = tid >> 2;
    const int fi = tid & 3;
    const int idx = (B0 + bl) * FDIM + F0 + fi;

    const double H = XSPAN / (GPTS - 1);
    double t = ((double)x[idx] - XMIN) * ((GPTS - 1) / XSPAN);
    t = fmin(fmax(t, 0.0), (double)(GPTS - 1));
    int i = (int)t;
    if (i > GPTS - 2) i = GPTS - 2;
    double w = t - (double)i;

    const int r0 = fi * GPTS + i;
    double u0 = tab[r0][0],     u1 = tab[r0 + 1][0];
    double c0 = tab[r0][1],     c1 = tab[r0 + 1][1];
    double m0 = tab[r0][2],     m1 = tab[r0 + 1][2];

    double w2 = w * w, w3 = w2 * w;
    double h00 = 2.0 * w3 - 3.0 * w2 + 1.0;
    double h10 = w3 - 2.0 * w2 + w;
    double h01 = 3.0 * w2 - 2.0 * w3;
    double h11 = w3 - w2;
    double dterm = H * (h10 * m0 + h11 * m1);
    double u  = h00 * u0 + h01 * u1 + dterm;
    double cu = h00 * c0 + h01 * c1 - dterm;

    out[idx] = (float)ndtri_pair(u, cu);
}

extern "C" void kernel_launch(void* const* d_in, const int* in_sizes, int n_in,
                              void* d_out, int out_size, void* d_ws, size_t ws_size,
                              hipStream_t stream) {
    const float* x   = (const float*)d_in[0];   // [512,128]
    const float* cdf = (const float*)d_in[1];   // [2048,128]
    const float* bwp = (const float*)d_in[2];   // [1,128]
    float* out = (float*)d_out;

    float4* part4 = (float4*)d_ws;              // 128*768*16B = 1.5MB

    build_kernel<<<dim3(GPTS * SP), dim3(BLOCK1), 0, stream>>>(cdf, bwp, part4);
    interp_kernel<<<dim3((FDIM / FG) * (BDIM / BG)), dim3(BLOCK2), 0, stream>>>(
        x, bwp, part4, out);
}

// Round 8
// 69.244 us; speedup vs baseline: 1.2697x; 1.0377x over previous
//
#include <hip/hip_runtime.h>
#include <math.h>

// BatchPitNorm1d — B=512, S=2048, F=128
//   u[b,f] = mean_s Phi((x[b,f]-cdf[s,f]) / sigmoid(bwp[f]));  out = ndtri(u)
//
// Table method, 2 kernels:
//  K1: fp32 partial sums of (Phi, exp(-z^2/2)) over 32-sample chunks on a
//      G=40 uniform x-grid; stored feature-major [f][sp][g] float2 so K2's
//      slab copy is contiguous. Direct Phi accumulation is safe: 32-sample
//      fp32 chunks + fp64 combine give <=3.4e-5 abs error on the 2048-sum ->
//      0.17% tail-relative -> <=2e-4 output error (npos tracking removed).
//  K2 (fused): each block owns 2 features x 128 batch rows: coalesced copy of
//      its 20KB partial slab -> LDS, sp-reduction -> fp64 (u,1-u,du/dx) table
//      in LDS, cubic Hermite (exact analytic slopes) + fp64 pair-ndtri.
//      (R5 lesson: never gather per-lane-divergent partial rows from global.)
// Error model (h^4, validated R4->R7 modulo the checker's 2^n quantization):
// G=40 (h=12/39) -> ~0.036 vs threshold 0.08.
#define FDIM  128
#define SDIM  2048
#define BDIM  512
#define GPTS  40
#define SP    32
#define PARTS 2
#define BLOCK1 (FDIM * PARTS)   // 256
#define XMIN  (-6.0)
#define XSPAN (12.0)
#define FG    2                 // features per K2 block
#define BG    128               // batch rows per K2 block
#define BLOCK2 256
#define PERF  (SP * GPTS)       // 1280 float2 entries per feature (10KB)

// ---------------- AS241 (Wichura) PPND16 inverse normal CDF, fp64 ----------
__device__ __forceinline__ double ndtri_pair(double u, double cu) {
    double q = u - 0.5;
    if (fabs(q) <= 0.425) {
        double r = 0.180625 - q * q;
        double num = (((((((2.5090809287301226727e3  * r + 3.3430575583588128105e4) * r +
                            6.7265770927008700853e4) * r + 4.5921953931549871457e4) * r +
                            1.3731693765509461125e4) * r + 1.9715909503065514427e3) * r +
                            1.3314166789178437745e2) * r + 3.3871328727963666080e0);
        double den = (((((((5.2264952788528545610e3  * r + 2.8729085735721942674e4) * r +
                            3.9307895800092710610e4) * r + 2.1213794301586595867e4) * r +
                            5.3941960214247511077e3) * r + 6.8718700749205790830e2) * r +
                            4.2313330701600911252e1) * r + 1.0);
        return q * num / den;
    }
    double r = (q < 0.0) ? u : cu;
    r = fmax(r, 1e-300);
    r = sqrt(-log(r));
    double val;
    if (r <= 5.0) {
        r -= 1.6;
        double num = (((((((7.74545014278341407640e-4 * r + 2.27238449892691845833e-2) * r +
                            2.41780725177450611770e-1) * r + 1.27045825245236838258e0) * r +
                            3.64784832476320460504e0)  * r + 5.76949722146069140550e0) * r +
                            4.63033784615654529590e0)  * r + 1.42343711074968357734e0);
        double den = (((((((1.05075007164441684324e-9 * r + 5.47593808499534494600e-4) * r +
                            1.51986665636164571966e-2) * r + 1.48103976427480074590e-1) * r +
                            6.89767334985100004550e-1) * r + 1.67638483018380384940e0) * r +
                            2.05319162663775882187e0)  * r + 1.0);
        val = num / den;
    } else {
        r -= 5.0;
        double num = (((((((2.01033439929228813265e-7 * r + 2.71155556874348757815e-5) * r +
                            1.24266094738807843860e-3) * r + 2.65321895265761230930e-2) * r +
                            2.96560571828504891230e-1) * r + 1.78482653991729133580e0) * r +
                            5.46378491116411436990e0)  * r + 6.65790464350110377720e0);
        double den = (((((((2.04426310338993978564e-15 * r + 1.42151175831644588870e-7) * r +
                            1.84631831751005468180e-5)  * r + 7.86869131145613259100e-4) * r +
                            1.48753612908506148525e-2)  * r + 1.36929880922735805310e-1) * r +
                            5.99832206555887937690e-1)  * r + 1.0);
        val = num / den;
    }
    return (q < 0.0) ? -val : val;
}

// ---------- K1: per-(gridpoint, S-chunk) partial sums -----------------------
// blockIdx.x = g*SP + sp; 256 threads = 128 f x 2 parts; 32 samples/thread.
// 1280 blocks -> exactly 5 blocks/CU (20 waves/CU).
__global__ __launch_bounds__(BLOCK1) void build_kernel(
    const float* __restrict__ cdf, const float* __restrict__ bwp,
    float2* __restrict__ part2)
{
    const int g    = blockIdx.x >> 5;          // /SP
    const int sp   = blockIdx.x & (SP - 1);
    const int f    = threadIdx.x & (FDIM - 1);
    const int part = threadIdx.x >> 7;

    const float p = bwp[f];
    const float s = (1.0f + __expf(-p)) * 0.70710678118654752f;  // invbw/sqrt2
    const float c1s    = 0.3275911f * s;                         // t-arg scale
    const float negs2l = -(s * s) * 1.4426950408889634f;         // exp2 arg scale
    const float xg = (float)(XMIN + (double)g * (XSPAN / (GPTS - 1)));

    const int chunk = SDIM / SP / PARTS;       // 32 samples
    const int base  = sp * (SDIM / SP) + part * chunk;
    const float* cp = cdf + base * FDIM + f;

    // Phi(z) = (z>=0) ? 1-e : e,  e = 0.5*erfc(|z|/sqrt2) (A&S 7.1.26, ~7.5e-8)
    float acc0 = 0.f, acc1 = 0.f, acc2 = 0.f, acc3 = 0.f;
    float dac = 0.f;

    #pragma unroll 2
    for (int i = 0; i < chunk; i += 4) {
        float c0 = cp[0 * FDIM];
        float c1 = cp[1 * FDIM];
        float c2 = cp[2 * FDIM];
        float c3 = cp[3 * FDIM];
        cp += 4 * FDIM;

        float d0 = xg - c0, d1 = xg - c1, d2 = xg - c2, d3 = xg - c3;

        float t0 = __builtin_amdgcn_rcpf(fmaf(c1s, fabsf(d0), 1.0f));
        float t1 = __builtin_amdgcn_rcpf(fmaf(c1s, fabsf(d1), 1.0f));
        float t2 = __builtin_amdgcn_rcpf(fmaf(c1s, fabsf(d2), 1.0f));
        float t3 = __builtin_amdgcn_rcpf(fmaf(c1s, fabsf(d3), 1.0f));

        float x0 = exp2f(d0 * d0 * negs2l);
        float x1 = exp2f(d1 * d1 * negs2l);
        float x2 = exp2f(d2 * d2 * negs2l);
        float x3 = exp2f(d3 * d3 * negs2l);

        float q0 = fmaf(0.53070271450f, t0, -0.72657601350f);
        float q1 = fmaf(0.53070271450f, t1, -0.72657601350f);
        float q2 = fmaf(0.53070271450f, t2, -0.72657601350f);
        float q3 = fmaf(0.53070271450f, t3, -0.72657601350f);
        q0 = fmaf(q0, t0, 0.71070687050f);  q1 = fmaf(q1, t1, 0.71070687050f);
        q2 = fmaf(q2, t2, 0.71070687050f);  q3 = fmaf(q3, t3, 0.71070687050f);
        q0 = fmaf(q0, t0, -0.14224836800f); q1 = fmaf(q1, t1, -0.14224836800f);
        q2 = fmaf(q2, t2, -0.14224836800f); q3 = fmaf(q3, t3, -0.14224836800f);
        q0 = fmaf(q0, t0, 0.12741479600f);  q1 = fmaf(q1, t1, 0.12741479600f);
        q2 = fmaf(q2, t2, 0.12741479600f);  q3 = fmaf(q3, t3, 0.12741479600f);

        float e0 = q0 * t0 * x0;
        float e1 = q1 * t1 * x1;
        float e2 = q2 * t2 * x2;
        float e3 = q3 * t3 * x3;

        acc0 += (d0 >= 0.f) ? (1.0f - e0) : e0;
        acc1 += (d1 >= 0.f) ? (1.0f - e1) : e1;
        acc2 += (d2 >= 0.f) ? (1.0f - e2) : e2;
        acc3 += (d3 >= 0.f) ? (1.0f - e3) : e3;
        dac  += (x0 + x1) + (x2 + x3);         // sum exp(-z^2/2) for du/dx
    }

    __shared__ float sacc[PARTS][FDIM];
    __shared__ float sdac[PARTS][FDIM];
    sacc[part][f] = (acc0 + acc1) + (acc2 + acc3);
    sdac[part][f] = dac;
    __syncthreads();

    if (part == 0) {
        float a  = sacc[0][f] + sacc[1][f];
        float da = sdac[0][f] + sdac[1][f];
        // feature-major [f][sp][g]: scattered 8B store (fire-and-forget) so K2's
        // per-feature slab copy is perfectly contiguous.
        part2[f * PERF + sp * GPTS + g] = make_float2(a, da);
    }
}

// ---------- K2 (fused): slab->LDS, sp-reduce, fp64 table, Hermite + ndtri ----
// grid = 64 f-groups x 4 b-groups = 256 blocks x 256 threads.
__global__ __launch_bounds__(BLOCK2) void interp_kernel(
    const float* __restrict__ x, const float* __restrict__ bwp,
    const float2* __restrict__ part2, float* __restrict__ out)
{
    const int fg = blockIdx.x & 63;
    const int bg = blockIdx.x >> 6;
    const int F0 = fg * FG;
    const int B0 = bg * BG;
    const int tid = threadIdx.x;

    __shared__ float2 sp2[FG * PERF];          // 2560 * 8B = 20KB
    __shared__ double tab[FG * GPTS][3];       // 80 * 24B = 1.9KB

    // phase 1: contiguous coalesced copy of this block's 2-feature slab
    const float2* src = part2 + (size_t)F0 * PERF;
    #pragma unroll
    for (int k = tid; k < FG * PERF; k += BLOCK2) sp2[k] = src[k];
    __syncthreads();

    // phase 2: reduce SP partials per (fi,g) row in fp64
    if (tid < FG * GPTS) {                     // 80 rows
        const int fi = tid / GPTS;
        const int g  = tid - fi * GPTS;
        double a = 0.0, da = 0.0;
        const int base = fi * PERF + g;
        #pragma unroll
        for (int sp = 0; sp < SP; ++sp) {
            float2 v = sp2[base + sp * GPTS];
            a  += (double)v.x;                 // sum Phi
            da += (double)v.y;                 // sum exp(-z^2/2)
        }
        const double invS = 1.0 / (double)SDIM;
        const double invbw = 1.0 + exp(-(double)bwp[F0 + fi]);
        tab[tid][0] = a * invS;                          // u
        tab[tid][1] = ((double)SDIM - a) * invS;         // 1-u
        tab[tid][2] = da * invbw * (invS / 2.5066282746310002);  // du/dx
    }
    __syncthreads();

    // phase 3: interpolate + ndtri; 1 output per thread
    const int bl = tid >> 1;                   // 0..127
    const int fi = tid & 1;
    const int idx = (B0 + bl) * FDIM + F0 + fi;

    const double H = XSPAN / (GPTS - 1);
    double t = ((double)x[idx] - XMIN) * ((GPTS - 1) / XSPAN);
    t = fmin(fmax(t, 0.0), (double)(GPTS - 1));
    int i = (int)t;
    if (i > GPTS - 2) i = GPTS - 2;
    double w = t - (double)i;

    const int r0 = fi * GPTS + i;
    double u0 = tab[r0][0], u1 = tab[r0 + 1][0];
    double c0 = tab[r0][1], c1 = tab[r0 + 1][1];
    double m0 = tab[r0][2], m1 = tab[r0 + 1][2];

    double w2 = w * w, w3 = w2 * w;
    double h00 = 2.0 * w3 - 3.0 * w2 + 1.0;
    double h10 = w3 - 2.0 * w2 + w;
    double h01 = 3.0 * w2 - 2.0 * w3;
    double h11 = w3 - w2;
    double dterm = H * (h10 * m0 + h11 * m1);
    double u  = h00 * u0 + h01 * u1 + dterm;
    double cu = h00 * c0 + h01 * c1 - dterm;

    out[idx] = (float)ndtri_pair(u, cu);
}

extern "C" void kernel_launch(void* const* d_in, const int* in_sizes, int n_in,
                              void* d_out, int out_size, void* d_ws, size_t ws_size,
                              hipStream_t stream) {
    const float* x   = (const float*)d_in[0];   // [512,128]
    const float* cdf = (const float*)d_in[1];   // [2048,128]
    const float* bwp = (const float*)d_in[2];   // [1,128]
    float* out = (float*)d_out;

    float2* part2 = (float2*)d_ws;              // 128*1280*8B = 1.31MB

    build_kernel<<<dim3(GPTS * SP), dim3(BLOCK1), 0, stream>>>(cdf, bwp, part2);
    interp_kernel<<<dim3((FDIM / FG) * (BDIM / BG)), dim3(BLOCK2), 0, stream>>>(
        x, bwp, part2, out);
}

// Round 9
// 66.808 us; speedup vs baseline: 1.3160x; 1.0364x over previous
//
#include <hip/hip_runtime.h>
#include <math.h>

// BatchPitNorm1d — B=512, S=2048, F=128
//   u[b,f] = mean_s Phi((x[b,f]-cdf[s,f]) / sigmoid(bwp[f]));  out = ndtri(u)
//
// Table method, 2 kernels:
//  K1: fp32 partial sums of (Phi, exp(-z^2/2)) over 32-sample chunks on a
//      G=32 uniform x-grid; stored feature-major [f][sp][g] float2 so K2's
//      slab copy is contiguous. 32-sample fp32 chunks + fp64 combine keep the
//      2048-sum at <=3.4e-5 abs error -> <=2e-4 output error.
//  K2 (fused): each block owns 2 features x 128 batch rows: coalesced copy of
//      its 16KB partial slab -> LDS, sp-reduction -> fp64 (u,1-u,du/dx) table
//      in LDS, cubic Hermite (exact analytic slopes) + fp64 pair-ndtri.
//      (R5 lesson: never gather per-lane-divergent partial rows from global.)
// Error budget: reported absmax was 2^-6 at G=40; pessimistic h^4 scaling to
// G=32 gives ~0.039 vs threshold 0.08 (measured trend suggests lower).
#define FDIM  128
#define SDIM  2048
#define BDIM  512
#define GPTS  32
#define SP    32
#define PARTS 2
#define BLOCK1 (FDIM * PARTS)   // 256
#define XMIN  (-6.0)
#define XSPAN (12.0)
#define FG    2                 // features per K2 block
#define BG    128               // batch rows per K2 block
#define BLOCK2 256
#define PERF  (SP * GPTS)       // 1024 float2 entries per feature (8KB)

// ---------------- AS241 (Wichura) PPND16 inverse normal CDF, fp64 ----------
__device__ __forceinline__ double ndtri_pair(double u, double cu) {
    double q = u - 0.5;
    if (fabs(q) <= 0.425) {
        double r = 0.180625 - q * q;
        double num = (((((((2.5090809287301226727e3  * r + 3.3430575583588128105e4) * r +
                            6.7265770927008700853e4) * r + 4.5921953931549871457e4) * r +
                            1.3731693765509461125e4) * r + 1.9715909503065514427e3) * r +
                            1.3314166789178437745e2) * r + 3.3871328727963666080e0);
        double den = (((((((5.2264952788528545610e3  * r + 2.8729085735721942674e4) * r +
                            3.9307895800092710610e4) * r + 2.1213794301586595867e4) * r +
                            5.3941960214247511077e3) * r + 6.8718700749205790830e2) * r +
                            4.2313330701600911252e1) * r + 1.0);
        return q * num / den;
    }
    double r = (q < 0.0) ? u : cu;
    r = fmax(r, 1e-300);
    r = sqrt(-log(r));
    double val;
    if (r <= 5.0) {
        r -= 1.6;
        double num = (((((((7.74545014278341407640e-4 * r + 2.27238449892691845833e-2) * r +
                            2.41780725177450611770e-1) * r + 1.27045825245236838258e0) * r +
                            3.64784832476320460504e0)  * r + 5.76949722146069140550e0) * r +
                            4.63033784615654529590e0)  * r + 1.42343711074968357734e0);
        double den = (((((((1.05075007164441684324e-9 * r + 5.47593808499534494600e-4) * r +
                            1.51986665636164571966e-2) * r + 1.48103976427480074590e-1) * r +
                            6.89767334985100004550e-1) * r + 1.67638483018380384940e0) * r +
                            2.05319162663775882187e0)  * r + 1.0);
        val = num / den;
    } else {
        r -= 5.0;
        double num = (((((((2.01033439929228813265e-7 * r + 2.71155556874348757815e-5) * r +
                            1.24266094738807843860e-3) * r + 2.65321895265761230930e-2) * r +
                            2.96560571828504891230e-1) * r + 1.78482653991729133580e0) * r +
                            5.46378491116411436990e0)  * r + 6.65790464350110377720e0);
        double den = (((((((2.04426310338993978564e-15 * r + 1.42151175831644588870e-7) * r +
                            1.84631831751005468180e-5)  * r + 7.86869131145613259100e-4) * r +
                            1.48753612908506148525e-2)  * r + 1.36929880922735805310e-1) * r +
                            5.99832206555887937690e-1)  * r + 1.0);
        val = num / den;
    }
    return (q < 0.0) ? -val : val;
}

// ---------- K1: per-(gridpoint, S-chunk) partial sums -----------------------
// blockIdx.x = g*SP + sp; 256 threads = 128 f x 2 parts; 32 samples/thread.
// 1024 blocks -> exactly 4 blocks/CU.
__global__ __launch_bounds__(BLOCK1) void build_kernel(
    const float* __restrict__ cdf, const float* __restrict__ bwp,
    float2* __restrict__ part2)
{
    const int g    = blockIdx.x >> 5;          // /SP
    const int sp   = blockIdx.x & (SP - 1);
    const int f    = threadIdx.x & (FDIM - 1);
    const int part = threadIdx.x >> 7;

    const float p = bwp[f];
    const float s = (1.0f + __expf(-p)) * 0.70710678118654752f;  // invbw/sqrt2
    const float c1s    = 0.3275911f * s;                         // t-arg scale
    const float negs2l = -(s * s) * 1.4426950408889634f;         // exp2 arg scale
    const float xg = (float)(XMIN + (double)g * (XSPAN / (GPTS - 1)));

    const int chunk = SDIM / SP / PARTS;       // 32 samples
    const int base  = sp * (SDIM / SP) + part * chunk;
    const float* cp = cdf + base * FDIM + f;

    // Phi(z) = (z>=0) ? 1-e : e,  e = 0.5*erfc(|z|/sqrt2) (A&S 7.1.26, ~7.5e-8)
    float acc0 = 0.f, acc1 = 0.f, acc2 = 0.f, acc3 = 0.f;
    float dac = 0.f;

    #pragma unroll 2
    for (int i = 0; i < chunk; i += 4) {
        float c0 = cp[0 * FDIM];
        float c1 = cp[1 * FDIM];
        float c2 = cp[2 * FDIM];
        float c3 = cp[3 * FDIM];
        cp += 4 * FDIM;

        float d0 = xg - c0, d1 = xg - c1, d2 = xg - c2, d3 = xg - c3;

        float t0 = __builtin_amdgcn_rcpf(fmaf(c1s, fabsf(d0), 1.0f));
        float t1 = __builtin_amdgcn_rcpf(fmaf(c1s, fabsf(d1), 1.0f));
        float t2 = __builtin_amdgcn_rcpf(fmaf(c1s, fabsf(d2), 1.0f));
        float t3 = __builtin_amdgcn_rcpf(fmaf(c1s, fabsf(d3), 1.0f));

        float x0 = exp2f(d0 * d0 * negs2l);
        float x1 = exp2f(d1 * d1 * negs2l);
        float x2 = exp2f(d2 * d2 * negs2l);
        float x3 = exp2f(d3 * d3 * negs2l);

        float q0 = fmaf(0.53070271450f, t0, -0.72657601350f);
        float q1 = fmaf(0.53070271450f, t1, -0.72657601350f);
        float q2 = fmaf(0.53070271450f, t2, -0.72657601350f);
        float q3 = fmaf(0.53070271450f, t3, -0.72657601350f);
        q0 = fmaf(q0, t0, 0.71070687050f);  q1 = fmaf(q1, t1, 0.71070687050f);
        q2 = fmaf(q2, t2, 0.71070687050f);  q3 = fmaf(q3, t3, 0.71070687050f);
        q0 = fmaf(q0, t0, -0.14224836800f); q1 = fmaf(q1, t1, -0.14224836800f);
        q2 = fmaf(q2, t2, -0.14224836800f); q3 = fmaf(q3, t3, -0.14224836800f);
        q0 = fmaf(q0, t0, 0.12741479600f);  q1 = fmaf(q1, t1, 0.12741479600f);
        q2 = fmaf(q2, t2, 0.12741479600f);  q3 = fmaf(q3, t3, 0.12741479600f);

        float e0 = q0 * t0 * x0;
        float e1 = q1 * t1 * x1;
        float e2 = q2 * t2 * x2;
        float e3 = q3 * t3 * x3;

        acc0 += (d0 >= 0.f) ? (1.0f - e0) : e0;
        acc1 += (d1 >= 0.f) ? (1.0f - e1) : e1;
        acc2 += (d2 >= 0.f) ? (1.0f - e2) : e2;
        acc3 += (d3 >= 0.f) ? (1.0f - e3) : e3;
        dac  += (x0 + x1) + (x2 + x3);         // sum exp(-z^2/2) for du/dx
    }

    __shared__ float sacc[PARTS][FDIM];
    __shared__ float sdac[PARTS][FDIM];
    sacc[part][f] = (acc0 + acc1) + (acc2 + acc3);
    sdac[part][f] = dac;
    __syncthreads();

    if (part == 0) {
        float a  = sacc[0][f] + sacc[1][f];
        float da = sdac[0][f] + sdac[1][f];
        // feature-major [f][sp][g]: scattered 8B store (fire-and-forget) so K2's
        // per-feature slab copy is perfectly contiguous.
        part2[f * PERF + sp * GPTS + g] = make_float2(a, da);
    }
}

// ---------- K2 (fused): slab->LDS, sp-reduce, fp64 table, Hermite + ndtri ----
// grid = 64 f-groups x 4 b-groups = 256 blocks x 256 threads.
__global__ __launch_bounds__(BLOCK2) void interp_kernel(
    const float* __restrict__ x, const float* __restrict__ bwp,
    const float2* __restrict__ part2, float* __restrict__ out)
{
    const int fg = blockIdx.x & 63;
    const int bg = blockIdx.x >> 6;
    const int F0 = fg * FG;
    const int B0 = bg * BG;
    const int tid = threadIdx.x;

    __shared__ float2 sp2[FG * PERF];          // 2048 * 8B = 16KB
    __shared__ double tab[FG * GPTS][3];       // 64 * 24B = 1.5KB

    // phase 1: contiguous coalesced copy of this block's 2-feature slab
    const float2* src = part2 + (size_t)F0 * PERF;
    #pragma unroll
    for (int k = tid; k < FG * PERF; k += BLOCK2) sp2[k] = src[k];
    __syncthreads();

    // phase 2: reduce SP partials per (fi,g) row in fp64
    if (tid < FG * GPTS) {                     // 64 rows
        const int fi = tid >> 5;               // /GPTS
        const int g  = tid & (GPTS - 1);
        double a = 0.0, da = 0.0;
        const int base = fi * PERF + g;
        #pragma unroll
        for (int sp = 0; sp < SP; ++sp) {
            float2 v = sp2[base + sp * GPTS];
            a  += (double)v.x;                 // sum Phi
            da += (double)v.y;                 // sum exp(-z^2/2)
        }
        const double invS = 1.0 / (double)SDIM;
        const double invbw = 1.0 + exp(-(double)bwp[F0 + fi]);
        tab[tid][0] = a * invS;                          // u
        tab[tid][1] = ((double)SDIM - a) * invS;         // 1-u
        tab[tid][2] = da * invbw * (invS / 2.5066282746310002);  // du/dx
    }
    __syncthreads();

    // phase 3: interpolate + ndtri; 1 output per thread
    const int bl = tid >> 1;                   // 0..127
    const int fi = tid & 1;
    const int idx = (B0 + bl) * FDIM + F0 + fi;

    const double H = XSPAN / (GPTS - 1);
    double t = ((double)x[idx] - XMIN) * ((GPTS - 1) / XSPAN);
    t = fmin(fmax(t, 0.0), (double)(GPTS - 1));
    int i = (int)t;
    if (i > GPTS - 2) i = GPTS - 2;
    double w = t - (double)i;

    const int r0 = fi * GPTS + i;
    double u0 = tab[r0][0], u1 = tab[r0 + 1][0];
    double c0 = tab[r0][1], c1 = tab[r0 + 1][1];
    double m0 = tab[r0][2], m1 = tab[r0 + 1][2];

    double w2 = w * w, w3 = w2 * w;
    double h00 = 2.0 * w3 - 3.0 * w2 + 1.0;
    double h10 = w3 - 2.0 * w2 + w;
    double h01 = 3.0 * w2 - 2.0 * w3;
    double h11 = w3 - w2;
    double dterm = H * (h10 * m0 + h11 * m1);
    double u  = h00 * u0 + h01 * u1 + dterm;
    double cu = h00 * c0 + h01 * c1 - dterm;

    out[idx] = (float)ndtri_pair(u, cu);
}

extern "C" void kernel_launch(void* const* d_in, const int* in_sizes, int n_in,
                              void* d_out, int out_size, void* d_ws, size_t ws_size,
                              hipStream_t stream) {
    const float* x   = (const float*)d_in[0];   // [512,128]
    const float* cdf = (const float*)d_in[1];   // [2048,128]
    const float* bwp = (const float*)d_in[2];   // [1,128]
    float* out = (float*)d_out;

    float2* part2 = (float2*)d_ws;              // 128*1024*8B = 1.0MB

    build_kernel<<<dim3(GPTS * SP), dim3(BLOCK1), 0, stream>>>(cdf, bwp, part2);
    interp_kernel<<<dim3((FDIM / FG) * (BDIM / BG)), dim3(BLOCK2), 0, stream>>>(
        x, bwp, part2, out);
}